// Round 13
// baseline (40.816 us; speedup 1.0000x reference)
//
#include <hip/hip_runtime.h>
#include <math.h>

#define NC 2048            // 2H + 2W (H = W = 512)
#define NB 4
#define NS 4096
#define INV_TEMP (1.0f / 256.0f)
#define LOG2E 1.44269504088896340736f
#define CL 16              // chunk length (rows per loss block)
#define NCH (NS / CL)      // 256 chunks per batch
#define P1_NG 16           // scan groups per P1 block (512 thr / 32 ch)
#define P1_GS (NS / P1_NG) // 256 s per group
#define P1_GC (P1_GS / CL) // 16 chunks per group
#define LOSS_NBLK (NB * NCH)   // 1024 loss blocks

typedef float f32x4 __attribute__((ext_vector_type(4)));
typedef float f32x2 __attribute__((ext_vector_type(2)));
typedef short s16x4 __attribute__((ext_vector_type(4)));

// ---------------------------------------------------------------------------
// Phase 1: per-(b, 32-channel tile) block. p in {0,1} exactly -> per step
// this block's segment is active iff p[s]==(seg&1); enc = hot in-segment
// channel (or -1). SPLIT packed streams: decs[f32] (16 KB) + encs[s16] (8 KB)
// overlaid on the staging buffer -> inner loop does 4 steps per
// {ds_read_b128 + ds_read_b64} (was 2 steps per b128): ~25% fewer LDS cycles.
// ---------------------------------------------------------------------------
__global__ __launch_bounds__(512) void tdl_scan_kernel(
    const float* __restrict__ target, float* __restrict__ rstart)
{
    const int b     = blockIdx.x >> 6;   // 64 channel-tiles per batch
    const int ctile = blockIdx.x & 63;
    const int tid = threadIdx.x;
    const int ci  = tid & 31;            // channel within tile
    const int g   = tid >> 5;            // scan group (0..15)

    __shared__ float shbuf[NS * 4];      // 64 KB staging; then decs+encs overlay
    __shared__ float shL[P1_NG][32];
    __shared__ float shG[P1_NG];
    f32x4* ev   = (f32x4*)shbuf;
    float* decs = shbuf;                 // [NS] f32
    short* encs = (short*)(shbuf + NS);  // [NS] s16

    const int  seg    = ctile >> 4;                       // 0..3
    const bool useH   = (seg < 2);
    const float segPar = (float)(seg & 1);
    const int  crel_i = ((ctile & 15) << 5) + ci;         // in-segment channel

    const float* tb = target + (size_t)b * NS * 4;

    // 1. stage target[b] as f32x4 {t,h,w,p}
#pragma unroll
    for (int m = 0; m < 8; ++m) {
        int s = m * 512 + tid;
        ev[s] = *((const f32x4*)tb + s);
    }
    __syncthreads();

    // 2. compute dec/enc in regs + my chunk alphas + group G (reads only)
    float dec_r[8];
    short enc_r[8];
#pragma unroll
    for (int m = 0; m < 8; ++m) {
        int s = m * 512 + tid;
        f32x4 e = ev[s];
        dec_r[m] = (s == NS - 1) ? 0.0f
                  : __expf(-(ev[s + 1].x - e.x) * INV_TEMP);
        enc_r[m] = (e.w == segPar) ? (short)(useH ? e.y : e.z) : (short)-1;
    }
    float alp[P1_GC];
    {
        const int gs = g * P1_GS;
#pragma unroll
        for (int q = 0; q < P1_GC; ++q) {
            int se = gs + q * CL;
            alp[q] = (g == P1_NG - 1 && q == P1_GC - 1) ? 0.0f
                     : __expf(-(ev[se + CL].x - ev[se].x) * INV_TEMP);
        }
        if (ci == 0) {
            shG[g] = (g == P1_NG - 1) ? 0.0f
                     : __expf(-(ev[gs + P1_GS].x - ev[gs].x) * INV_TEMP);
        }
    }
    __syncthreads();

    // 3. overwrite buffer with split streams
#pragma unroll
    for (int m = 0; m < 8; ++m) {
        int s = m * 512 + tid;
        decs[s] = dec_r[m];
        encs[s] = enc_r[m];
    }
    __syncthreads();

    // 4. per-chunk local suffix sums (zero carry); 4 steps per LDS read pair
    float cs[P1_GC];
    {
        const int gs = g * P1_GS;
#pragma unroll
        for (int q = P1_GC - 1; q >= 0; --q) {
            float v = 0.0f;
            const int base = gs + q * CL;
#pragma unroll
            for (int i = CL - 4; i >= 0; i -= 4) {
                f32x4 d4 = *(const f32x4*)&decs[base + i];
                s16x4 e4 = *(const s16x4*)&encs[base + i];
                v = fmaf(v, d4.w, (e4.w == crel_i) ? 1.0f : 0.0f);  // i+3
                v = fmaf(v, d4.z, (e4.z == crel_i) ? 1.0f : 0.0f);  // i+2
                v = fmaf(v, d4.y, (e4.y == crel_i) ? 1.0f : 0.0f);  // i+1
                v = fmaf(v, d4.x, (e4.x == crel_i) ? 1.0f : 0.0f);  // i
            }
            cs[q] = v;
        }
    }

    // 5. group-local combine -> L (value at group start, zero incoming)
    float L = 0.0f;
#pragma unroll
    for (int q = P1_GC - 1; q >= 0; --q) L = fmaf(alp[q], L, cs[q]);
    shL[g][ci] = L;
    __syncthreads();

    // 6. carry into group g = suffix over groups j > g
    float X = 0.0f;
#pragma unroll
    for (int j = P1_NG - 1; j >= 1; --j)
        if (j > g) X = fmaf(shG[j], X, shL[j][ci]);

    // 7. chunk-level replay with carry, store rstart[b, g*16+q, c]
    float* rs = rstart + ((size_t)b * NCH + g * P1_GC) * NC + (ctile * 32 + ci);
    float carry = X;
#pragma unroll
    for (int q = P1_GC - 1; q >= 0; --q) {
        carry = fmaf(alp[q], carry, cs[q]);
        rs[(size_t)q * NC] = carry;
    }
}

// ---------------------------------------------------------------------------
// Phase 2: fused scan + soft-CE loss, ACTIVE-SEGMENT ONLY (R11 structure:
// CL=16, 1024 blocks x 4 waves; wv = H/W-pair, rh splits rows 15..8 / 7..0).
// launch_bounds(256, 6): cap VGPR ~85 -> 6 waves/SIMD (was 4) to cover the
// shfl/trans reduction chain. R12's head fixes kept: early global p-loads,
// f32x4 ev staging, wave-uniform pv branch.
// ---------------------------------------------------------------------------
__global__ __launch_bounds__(256, 6) void tdl_loss_kernel(
    const float* __restrict__ pred, const float* __restrict__ target,
    const float* __restrict__ rstart, float* __restrict__ partials)
{
    const int blk = blockIdx.x;
    const int b = blk >> 8;              // / NCH
    const int k = blk & (NCH - 1);
    const int s0 = k * CL;
    const int tid = threadIdx.x;
    const int wv  = (tid >> 6) & 1;      // 0: H-pair, 1: W-pair
    const int rh  = tid >> 7;            // 0: rows 15..8, 1: rows 7..0
    const int ln  = tid & 63;

    __shared__ f32x4 evraw[CL + 1];      // staged {t,h,w,p}
    __shared__ f32x4 ev[CL];             // {dec, p, h, w}
    __shared__ float sh4[4];

    const int lc   = ln * 4;             // lane offset within a 256-ch quarter
    const int segA = wv * 2;             // even segment of my pair
    const size_t pbase = (size_t)b * NS * NC;
    const int itop = rh ? (CL / 2 - 1) : (CL - 1);  // 7 or 15

    // EARLY: p for my first two rows straight from global (independent of
    // LDS staging) -> first two pred prefetches issue before the barrier.
    const float pt0 = target[((size_t)b * NS + s0 + itop) * 4 + 3];
    const float pt1 = target[((size_t)b * NS + s0 + itop - 1) * 4 + 3];

    f32x4 pf0[2], pf1[2];
    {
        const float* pr = pred + pbase + (size_t)(s0 + itop) * NC
                          + (segA + (int)pt0) * 512 + lc;
        pf0[0] = *(const f32x4*)pr; pf0[1] = *(const f32x4*)(pr + 256);
        const float* pr2 = pred + pbase + (size_t)(s0 + itop - 1) * NC
                           + (segA + (int)pt1) * 512 + lc;
        pf1[0] = *(const f32x4*)pr2; pf1[1] = *(const f32x4*)(pr2 + 256);
    }

    // carry init = r[b,(k+1)*CL, my channels] (zero for last chunk)
    float vA[8], vB[8];
    if (k == NCH - 1) {
#pragma unroll
        for (int j = 0; j < 8; ++j) { vA[j] = 0.0f; vB[j] = 0.0f; }
    } else {
        const float* rrow = rstart + ((size_t)b * NCH + k + 1) * NC;
#pragma unroll
        for (int q = 0; q < 2; ++q) {
            f32x4 ra = *(const f32x4*)(rrow + segA * 512 + q * 256 + lc);
            f32x4 rb = *(const f32x4*)(rrow + (segA + 1) * 512 + q * 256 + lc);
#pragma unroll
            for (int j = 0; j < 4; ++j) {
                vA[q*4+j] = ra[j] * LOG2E;
                vB[q*4+j] = rb[j] * LOG2E;
            }
        }
    }

    // stage CL+1 raw event rows (vectorized f32x4, 17 threads, one round)
    if (tid <= CL) {
        int s = s0 + tid;
        if (s < NS) evraw[tid] = *((const f32x4*)target + (size_t)b * NS + s);
        else        { f32x4 z = {0,0,0,0}; evraw[tid] = z; }
    }
    __syncthreads();
    if (tid < CL) {
        f32x4 r = evraw[tid];
        int s = s0 + tid;
        float dec = (s == NS - 1 || s == 0) ? 0.0f
                   : __expf(-(evraw[tid + 1].x - r.x) * INV_TEMP);
        f32x4 e; e.x = dec; e.y = r.w; e.z = r.y; e.w = r.z;  // {dec,p,h,w}
        ev[tid] = e;
    }
    __syncthreads();

    // rh=1 waves: replay rows 15..8 scan-only to derive carry at row 7
    if (rh) {
#pragma unroll
        for (int i = CL - 1; i >= CL / 2; --i) {
            f32x4 e = ev[i];
            const float d    = e.x;
            const float pv   = e.y;
            const float idxf = wv ? e.w : e.z;
            const float aA = (1.0f - pv) * LOG2E;
            const float aB = pv * LOG2E;
#pragma unroll
            for (int q = 0; q < 2; ++q) {
#pragma unroll
                for (int j = 0; j < 4; ++j) {
                    const int id = q * 4 + j;
                    const float myc = (float)(q * 256 + lc + j);
                    const bool m = (idxf == myc);
                    vA[id] = fmaf(vA[id], d, m ? aA : 0.0f);
                    vB[id] = fmaf(vB[id], d, m ? aB : 0.0f);
                }
            }
        }
    }

    float acc = 0.0f;
#pragma unroll
    for (int i = itop; i > itop - CL / 2; --i) {
        f32x4 cur[2];
        cur[0] = pf0[0]; cur[1] = pf0[1];
        pf0[0] = pf1[0]; pf0[1] = pf1[1];
        if (i >= itop - (CL / 2 - 3)) {  // row i-2 still in my range
            const int pa = (int)ev[i - 2].y;
            const float* pr = pred + pbase + (size_t)(s0 + i - 2) * NC
                              + (segA + pa) * 512 + lc;
            pf1[0] = *(const f32x4*)pr; pf1[1] = *(const f32x4*)(pr + 256);
        }

        f32x4 e = ev[i];
        const float d    = e.x;
        const float pv   = e.y;                    // 0.0 or 1.0 exactly
        const float idxf = wv ? e.w : e.z;         // w for W-pair, h for H-pair
        const float aA = (1.0f - pv) * LOG2E;
        const float aB = pv * LOG2E;

        // scan update for both segments (always)
#pragma unroll
        for (int q = 0; q < 2; ++q) {
#pragma unroll
            for (int j = 0; j < 4; ++j) {
                const int id = q * 4 + j;
                const float myc = (float)(q * 256 + lc + j);
                const bool m = (idxf == myc);
                vA[id] = fmaf(vA[id], d, m ? aA : 0.0f);
                vB[id] = fmaf(vB[id], d, m ? aB : 0.0f);
            }
        }

        // loss body for the ACTIVE segment only (wave-uniform branch)
        float ser = 0.0f, dot = 0.0f, sep = 0.0f;
#define ROW_BODY(V)                                                        \
        _Pragma("unroll")                                                  \
        for (int q = 0; q < 2; ++q) {                                      \
            _Pragma("unroll")                                              \
            for (int j = 0; j < 4; ++j) {                                  \
                const float ex = exp2f(V[q * 4 + j]);                      \
                const float pj = cur[q][j];                                \
                ser += ex;                                                 \
                dot = fmaf(ex, pj, dot);                                   \
                sep += __expf(pj);                                         \
            }                                                              \
        }
        if (pv != 0.0f) { ROW_BODY(vB) } else { ROW_BODY(vA) }
#undef ROW_BODY

        // full-wave 64-lane reductions (active segment = 512 ch = 64 x 8)
#pragma unroll
        for (int off = 32; off > 0; off >>= 1) {
            ser += __shfl_xor(ser, off, 64);
            dot += __shfl_xor(dot, off, 64);
            sep += __shfl_xor(sep, off, 64);
        }
        acc += __logf(sep) - dot * __builtin_amdgcn_rcpf(ser);
    }

    if (ln == 0) sh4[tid >> 6] = acc;    // one writer per wave
    __syncthreads();
    if (tid == 0) partials[blk] = sh4[0] + sh4[1] + sh4[2] + sh4[3];
}

// ---------------------------------------------------------------------------
// Phase 3: tiny reduce — 1 block, 256 threads, 4 KB of partials -> out[0].
// ---------------------------------------------------------------------------
__global__ __launch_bounds__(256) void tdl_reduce_kernel(
    const float* __restrict__ partials, float* __restrict__ out)
{
    const int tid = threadIdx.x;
    __shared__ float sh4[4];

    float s = 0.0f;
#pragma unroll
    for (int i = 0; i < LOSS_NBLK / 256; ++i)
        s += partials[i * 256 + tid];
#pragma unroll
    for (int off = 32; off > 0; off >>= 1)
        s += __shfl_xor(s, off, 64);
    if ((tid & 63) == 0) sh4[tid >> 6] = s;
    __syncthreads();
    if (tid == 0)
        out[0] = (sh4[0] + sh4[1] + sh4[2] + sh4[3])
                 * (1.0f / ((float)NB * (float)NS));
}

// ---------------------------------------------------------------------------
extern "C" void kernel_launch(void* const* d_in, const int* in_sizes, int n_in,
                              void* d_out, int out_size, void* d_ws, size_t ws_size,
                              hipStream_t stream)
{
    const float* pred   = (const float*)d_in[0];
    const float* target = (const float*)d_in[1];
    float* out    = (float*)d_out;
    float* rstart = (float*)d_ws;                       // 8 MiB
    float* partials = rstart + (size_t)NB * NCH * NC;   // 4 KiB

    tdl_scan_kernel<<<NB * 64, 512, 0, stream>>>(target, rstart);
    tdl_loss_kernel<<<NB * NCH, 256, 0, stream>>>(pred, target, rstart, partials);
    tdl_reduce_kernel<<<1, 256, 0, stream>>>(partials, out);
}

// Round 14
// 32.838 us; speedup vs baseline: 1.2430x; 1.2430x over previous
//
#include <hip/hip_runtime.h>
#include <math.h>

#define NC 2048            // 2H + 2W (H = W = 512)
#define NB 4
#define NS 4096
#define INV_TEMP (1.0f / 256.0f)
#define LOG2E 1.44269504088896340736f
#define CL 16              // chunk length (rows per loss block)
#define NCH (NS / CL)      // 256 chunks per batch
#define P1_NG 16           // scan groups per P1 block (512 thr / 32 ch)
#define P1_GS (NS / P1_NG) // 256 s per group
#define P1_GC (P1_GS / CL) // 16 chunks per group
#define LOSS_NBLK (NB * NCH)   // 1024 loss blocks

typedef float f32x4 __attribute__((ext_vector_type(4)));
typedef float f32x2 __attribute__((ext_vector_type(2)));

// ---------------------------------------------------------------------------
// Phase 1: per-(b, 32-channel tile) block.  (verbatim from R11, the 31.8 µs
// config.) p in {0,1} exactly -> pack {dec, enc} as f32x2 over the staged
// buffer; per-chunk suffix sums + hierarchical scan -> rstart.
// ---------------------------------------------------------------------------
__global__ __launch_bounds__(512) void tdl_scan_kernel(
    const float* __restrict__ target, float* __restrict__ rstart)
{
    const int b     = blockIdx.x >> 6;   // 64 channel-tiles per batch
    const int ctile = blockIdx.x & 63;
    const int tid = threadIdx.x;
    const int ci  = tid & 31;            // channel within tile
    const int g   = tid >> 5;            // scan group (0..15)

    __shared__ float shbuf[NS * 4];      // 64 KB: f32x4 ev[NS] then f32x2 pk[NS]
    __shared__ float shL[P1_NG][32];
    __shared__ float shG[P1_NG];
    f32x4* ev = (f32x4*)shbuf;
    f32x2* pk = (f32x2*)shbuf;

    const int  seg    = ctile >> 4;                       // 0..3
    const bool useH   = (seg < 2);
    const float segPar = (float)(seg & 1);
    const float crel  = (float)(((ctile & 15) << 5) + ci); // in-segment channel

    const float* tb = target + (size_t)b * NS * 4;

    // 1. stage target[b] as f32x4 {t,h,w,p}
#pragma unroll
    for (int m = 0; m < 8; ++m) {
        int s = m * 512 + tid;
        ev[s] = *((const f32x4*)tb + s);
    }
    __syncthreads();

    // 2. compute {dec, enc} in regs + my chunk alphas + group G (reads only)
    float dec_r[8], enc_r[8];
#pragma unroll
    for (int m = 0; m < 8; ++m) {
        int s = m * 512 + tid;
        f32x4 e = ev[s];
        dec_r[m] = (s == NS - 1) ? 0.0f
                  : __expf(-(ev[s + 1].x - e.x) * INV_TEMP);
        enc_r[m] = (e.w == segPar) ? (useH ? e.y : e.z) : -1.0f;
    }
    float alp[P1_GC];
    {
        const int gs = g * P1_GS;
#pragma unroll
        for (int q = 0; q < P1_GC; ++q) {
            int se = gs + q * CL;
            alp[q] = (g == P1_NG - 1 && q == P1_GC - 1) ? 0.0f
                     : __expf(-(ev[se + CL].x - ev[se].x) * INV_TEMP);
        }
        if (ci == 0) {
            shG[g] = (g == P1_NG - 1) ? 0.0f
                     : __expf(-(ev[gs + P1_GS].x - ev[gs].x) * INV_TEMP);
        }
    }
    __syncthreads();

    // 3. overwrite buffer with packed float2
#pragma unroll
    for (int m = 0; m < 8; ++m) {
        int s = m * 512 + tid;
        f32x2 v; v.x = dec_r[m]; v.y = enc_r[m];
        pk[s] = v;
    }
    __syncthreads();

    // 4. per-chunk local suffix sums (zero carry), 16 chunks in registers
    float cs[P1_GC];
    {
        const int gs = g * P1_GS;
#pragma unroll
        for (int q = P1_GC - 1; q >= 0; --q) {
            float v = 0.0f;
            const int base = gs + q * CL;
#pragma unroll
            for (int i = CL - 1; i >= 0; --i) {
                f32x2 e = pk[base + i];
                v = fmaf(v, e.x, (e.y == crel) ? 1.0f : 0.0f);
            }
            cs[q] = v;
        }
    }

    // 5. group-local combine -> L (value at group start, zero incoming)
    float L = 0.0f;
#pragma unroll
    for (int q = P1_GC - 1; q >= 0; --q) L = fmaf(alp[q], L, cs[q]);
    shL[g][ci] = L;
    __syncthreads();

    // 6. carry into group g = suffix over groups j > g
    float X = 0.0f;
#pragma unroll
    for (int j = P1_NG - 1; j >= 1; --j)
        if (j > g) X = fmaf(shG[j], X, shL[j][ci]);

    // 7. chunk-level replay with carry, store rstart[b, g*16+q, c]
    float* rs = rstart + ((size_t)b * NCH + g * P1_GC) * NC + (ctile * 32 + ci);
    float carry = X;
#pragma unroll
    for (int q = P1_GC - 1; q >= 0; --q) {
        carry = fmaf(alp[q], carry, cs[q]);
        rs[(size_t)q * NC] = carry;
    }
}

// ---------------------------------------------------------------------------
// Phase 2: fused scan + soft-CE loss, ACTIVE-SEGMENT ONLY (R11 structure:
// CL=16, 1024 blocks x 4 waves; wv = H/W-pair, rh = rows 15..8 / 7..0).
// NEW: BATCHED REDUCTIONS — the row loop only accumulates per-lane
// ser/dot/sep into 24 registers (no cross-lane ops); all 24 shfl trees run
// after the loop (independent per level -> throughput-bound, one tree
// latency total) followed by 8 log/rcp. Removes ~250 cyc/row of serial
// DS-latency stall. launch_bounds(256,4): VGPR<=128, no spills (R13's
// (256,6) forced <=85 and spilled, +9 us).
// ---------------------------------------------------------------------------
__global__ __launch_bounds__(256, 4) void tdl_loss_kernel(
    const float* __restrict__ pred, const float* __restrict__ target,
    const float* __restrict__ rstart, float* __restrict__ partials)
{
    const int blk = blockIdx.x;
    const int b = blk >> 8;              // / NCH
    const int k = blk & (NCH - 1);
    const int s0 = k * CL;
    const int tid = threadIdx.x;
    const int wv  = (tid >> 6) & 1;      // 0: H-pair, 1: W-pair
    const int rh  = tid >> 7;            // 0: rows 15..8, 1: rows 7..0
    const int ln  = tid & 63;

    __shared__ f32x4 ev[CL];             // {dec, p, h, w}
    __shared__ float sh4[4];

    if (tid < CL) {
        const float* tg = target + ((size_t)b * NS + s0 + tid) * 4;
        float t0 = tg[0];
        int s = s0 + tid;
        float dec = (s == NS - 1 || s == 0) ? 0.0f
                   : __expf(-(tg[4] - t0) * INV_TEMP);   // tg[4] = t[s+1]
        f32x4 e; e.x = dec; e.y = tg[3]; e.z = tg[1]; e.w = tg[2];
        ev[tid] = e;
    }
    __syncthreads();

    const int lc   = ln * 4;             // lane offset within a 256-ch quarter
    const int segA = wv * 2;             // even segment of my pair
    const size_t pbase = (size_t)b * NS * NC;

    // scan state (exp2 domain) for both segments of the pair
    float vA[8], vB[8];
    if (k == NCH - 1) {
#pragma unroll
        for (int j = 0; j < 8; ++j) { vA[j] = 0.0f; vB[j] = 0.0f; }
    } else {
        const float* rrow = rstart + ((size_t)b * NCH + k + 1) * NC;
#pragma unroll
        for (int q = 0; q < 2; ++q) {
            f32x4 ra = *(const f32x4*)(rrow + segA * 512 + q * 256 + lc);
            f32x4 rb = *(const f32x4*)(rrow + (segA + 1) * 512 + q * 256 + lc);
#pragma unroll
            for (int j = 0; j < 4; ++j) {
                vA[q*4+j] = ra[j] * LOG2E;
                vB[q*4+j] = rb[j] * LOG2E;
            }
        }
    }

    // rh=1 waves: replay rows 15..8 scan-only to derive carry at row 7
    if (rh) {
#pragma unroll
        for (int i = CL - 1; i >= CL / 2; --i) {
            f32x4 e = ev[i];
            const float d    = e.x;
            const float pv   = e.y;
            const float idxf = wv ? e.w : e.z;
            const float aA = (1.0f - pv) * LOG2E;
            const float aB = pv * LOG2E;
#pragma unroll
            for (int q = 0; q < 2; ++q) {
#pragma unroll
                for (int j = 0; j < 4; ++j) {
                    const int id = q * 4 + j;
                    const float myc = (float)(q * 256 + lc + j);
                    const bool m = (idxf == myc);
                    vA[id] = fmaf(vA[id], d, m ? aA : 0.0f);
                    vB[id] = fmaf(vB[id], d, m ? aB : 0.0f);
                }
            }
        }
    }

    const int itop = rh ? (CL / 2 - 1) : (CL - 1);  // 7 or 15

    // depth-2 prefetch of the ACTIVE segment's pred rows
    f32x4 pf0[2], pf1[2];
    {
        const int paT = (int)ev[itop].y;
        const float* pr = pred + pbase + (size_t)(s0 + itop) * NC
                          + (segA + paT) * 512 + lc;
        pf0[0] = *(const f32x4*)pr; pf0[1] = *(const f32x4*)(pr + 256);
        const int paU = (int)ev[itop - 1].y;
        const float* pr2 = pred + pbase + (size_t)(s0 + itop - 1) * NC
                           + (segA + paU) * 512 + lc;
        pf1[0] = *(const f32x4*)pr2; pf1[1] = *(const f32x4*)(pr2 + 256);
    }

    // Phase A: rows loop, per-lane partials only (no cross-lane ops)
    float serr[8], dotr[8], sepr[8];
#pragma unroll
    for (int r = 0; r < 8; ++r) {
        const int i = itop - r;
        f32x4 cur[2];
        cur[0] = pf0[0]; cur[1] = pf0[1];
        pf0[0] = pf1[0]; pf0[1] = pf1[1];
        if (r < 6) {                     // row i-2 still in my range
            const int pa = (int)ev[i - 2].y;
            const float* pr = pred + pbase + (size_t)(s0 + i - 2) * NC
                              + (segA + pa) * 512 + lc;
            pf1[0] = *(const f32x4*)pr; pf1[1] = *(const f32x4*)(pr + 256);
        }

        f32x4 e = ev[i];
        const float d    = e.x;
        const float pv   = e.y;                    // 0.0 or 1.0 exactly
        const float idxf = wv ? e.w : e.z;         // w for W-pair, h for H-pair
        const float aA = (1.0f - pv) * LOG2E;
        const float aB = pv * LOG2E;

        // scan update for both segments (always)
#pragma unroll
        for (int q = 0; q < 2; ++q) {
#pragma unroll
            for (int j = 0; j < 4; ++j) {
                const int id = q * 4 + j;
                const float myc = (float)(q * 256 + lc + j);
                const bool m = (idxf == myc);
                vA[id] = fmaf(vA[id], d, m ? aA : 0.0f);
                vB[id] = fmaf(vB[id], d, m ? aB : 0.0f);
            }
        }

        // per-lane partials for the ACTIVE segment (wave-uniform select)
        float ser = 0.0f, dot = 0.0f, sep = 0.0f;
#pragma unroll
        for (int q = 0; q < 2; ++q) {
#pragma unroll
            for (int j = 0; j < 4; ++j) {
                const int id = q * 4 + j;
                const float vs = (pv != 0.0f) ? vB[id] : vA[id];
                const float ex = exp2f(vs);
                const float pj = cur[q][j];
                ser += ex;
                dot = fmaf(ex, pj, dot);
                sep += __expf(pj);
            }
        }
        serr[r] = ser; dotr[r] = dot; sepr[r] = sep;
    }

    // Phase B: batched 64-lane reductions (24 independent trees per level)
#pragma unroll
    for (int off = 32; off > 0; off >>= 1) {
#pragma unroll
        for (int r = 0; r < 8; ++r) {
            serr[r] += __shfl_xor(serr[r], off, 64);
            dotr[r] += __shfl_xor(dotr[r], off, 64);
            sepr[r] += __shfl_xor(sepr[r], off, 64);
        }
    }
    float acc = 0.0f;
#pragma unroll
    for (int r = 0; r < 8; ++r)
        acc += __logf(sepr[r]) - dotr[r] * __builtin_amdgcn_rcpf(serr[r]);

    if (ln == 0) sh4[tid >> 6] = acc;    // one writer per wave
    __syncthreads();
    if (tid == 0) partials[blk] = sh4[0] + sh4[1] + sh4[2] + sh4[3];
}

// ---------------------------------------------------------------------------
// Phase 3: tiny reduce — 1 block, 256 threads, 4 KB of partials -> out[0].
// ---------------------------------------------------------------------------
__global__ __launch_bounds__(256) void tdl_reduce_kernel(
    const float* __restrict__ partials, float* __restrict__ out)
{
    const int tid = threadIdx.x;
    __shared__ float sh4[4];

    float s = 0.0f;
#pragma unroll
    for (int i = 0; i < LOSS_NBLK / 256; ++i)
        s += partials[i * 256 + tid];
#pragma unroll
    for (int off = 32; off > 0; off >>= 1)
        s += __shfl_xor(s, off, 64);
    if ((tid & 63) == 0) sh4[tid >> 6] = s;
    __syncthreads();
    if (tid == 0)
        out[0] = (sh4[0] + sh4[1] + sh4[2] + sh4[3])
                 * (1.0f / ((float)NB * (float)NS));
}

// ---------------------------------------------------------------------------
extern "C" void kernel_launch(void* const* d_in, const int* in_sizes, int n_in,
                              void* d_out, int out_size, void* d_ws, size_t ws_size,
                              hipStream_t stream)
{
    const float* pred   = (const float*)d_in[0];
    const float* target = (const float*)d_in[1];
    float* out    = (float*)d_out;
    float* rstart = (float*)d_ws;                       // 8 MiB
    float* partials = rstart + (size_t)NB * NCH * NC;   // 4 KiB

    tdl_scan_kernel<<<NB * 64, 512, 0, stream>>>(target, rstart);
    tdl_loss_kernel<<<NB * NCH, 256, 0, stream>>>(pred, target, rstart, partials);
    tdl_reduce_kernel<<<1, 256, 0, stream>>>(partials, out);
}

// Round 15
// 32.710 us; speedup vs baseline: 1.2478x; 1.0039x over previous
//
#include <hip/hip_runtime.h>
#include <math.h>

#define NC 2048            // 2H + 2W (H = W = 512)
#define NB 4
#define NS 4096
#define INV_TEMP (1.0f / 256.0f)
#define LOG2E 1.44269504088896340736f
#define CL 16              // chunk length (rows per loss block)
#define NCH (NS / CL)      // 256 chunks per batch
#define P1_NG 16           // scan groups per P1 block (512 thr / 32 ch)
#define P1_GS (NS / P1_NG) // 256 s per group
#define P1_GC (P1_GS / CL) // 16 chunks per group
#define LOSS_NBLK (NB * NCH)   // 1024 loss blocks

typedef float f32x4 __attribute__((ext_vector_type(4)));
typedef unsigned int u32x4 __attribute__((ext_vector_type(4)));

// ---------------------------------------------------------------------------
// Phase 1: per-(b, 32-channel tile) block.
// ALGEBRAIC CHANGE: no per-step dec chain. Telescoping:
//   cs[q] = sum_{i in chunk q} [enc_i == c] * exp(-(t_i - t_chunkstart)/TEMP)
// -> phase 4 is a PURE SUM (no serial fma dependency) over a 4 B/step packed
// stream: u32 = bf16(w) in high 16 | enc in low 16 (enc = hot in-segment
// channel or 0xFFFF). Halves the ds_read_b128 count vs the f32x2 {dec,enc}
// stream and shrinks the pk buffer to 16 KB. w is a SINGLE exp per step
// (no error compounding); bf16-RN error ~2e-3 relative -> loss shift ~1e-2.
// ---------------------------------------------------------------------------
__global__ __launch_bounds__(512) void tdl_scan_kernel(
    const float* __restrict__ target, float* __restrict__ rstart)
{
    const int b     = blockIdx.x >> 6;   // 64 channel-tiles per batch
    const int ctile = blockIdx.x & 63;
    const int tid = threadIdx.x;
    const int ci  = tid & 31;            // channel within tile
    const int g   = tid >> 5;            // scan group (0..15)

    __shared__ float shbuf[NS * 4];      // 64 KB staging; pk overlays first 16 KB
    __shared__ float shL[P1_NG][32];
    __shared__ float shG[P1_NG];
    f32x4* ev = (f32x4*)shbuf;
    unsigned* pku = (unsigned*)shbuf;

    const int  seg    = ctile >> 4;                       // 0..3
    const bool useH   = (seg < 2);
    const float segPar = (float)(seg & 1);
    const unsigned crel_u = (unsigned)(((ctile & 15) << 5) + ci);

    const float* tb = target + (size_t)b * NS * 4;

    // 1. stage target[b] as f32x4 {t,h,w,p}
#pragma unroll
    for (int m = 0; m < 8; ++m) {
        int s = m * 512 + tid;
        ev[s] = *((const f32x4*)tb + s);
    }
    __syncthreads();

    // 2. per-step packed {bf16 w | enc16} + chunk alphas + group G (reads only)
    unsigned pk_r[8];
#pragma unroll
    for (int m = 0; m < 8; ++m) {
        int s = m * 512 + tid;
        f32x4 e = ev[s];
        float tcs = ev[s & ~(CL - 1)].x;             // chunk-start time
        float w = __expf(-(e.x - tcs) * INV_TEMP);   // decay to chunk start
        unsigned uw = (__float_as_uint(w) + 0x8000u) & 0xFFFF0000u; // bf16 RN
        unsigned enc = (e.w == segPar)
                       ? (unsigned)(unsigned short)(short)(useH ? e.y : e.z)
                       : 0xFFFFu;
        pk_r[m] = uw | enc;
    }
    float alp[P1_GC];
    {
        const int gs = g * P1_GS;
#pragma unroll
        for (int q = 0; q < P1_GC; ++q) {
            int se = gs + q * CL;
            alp[q] = (g == P1_NG - 1 && q == P1_GC - 1) ? 0.0f
                     : __expf(-(ev[se + CL].x - ev[se].x) * INV_TEMP);
        }
        if (ci == 0) {
            shG[g] = (g == P1_NG - 1) ? 0.0f
                     : __expf(-(ev[gs + P1_GS].x - ev[gs].x) * INV_TEMP);
        }
    }
    __syncthreads();

    // 3. overwrite buffer head with packed u32 stream
#pragma unroll
    for (int m = 0; m < 8; ++m) pku[m * 512 + tid] = pk_r[m];
    __syncthreads();

    // 4. per-chunk sums (PURE SUM, no dependency); 4 steps per b128
    float cs[P1_GC];
    {
        const int gs = g * P1_GS;
#pragma unroll
        for (int q = P1_GC - 1; q >= 0; --q) {
            float v = 0.0f;
            const int base = gs + q * CL;
#pragma unroll
            for (int i = 0; i < CL; i += 4) {
                u32x4 u4 = *(const u32x4*)&pku[base + i];
#pragma unroll
                for (int jj = 0; jj < 4; ++jj) {
                    const unsigned u = u4[jj];
                    v += ((u & 0xFFFFu) == crel_u)
                         ? __uint_as_float(u & 0xFFFF0000u) : 0.0f;
                }
            }
            cs[q] = v;
        }
    }

    // 5. group-local combine -> L (value at group start, zero incoming)
    float L = 0.0f;
#pragma unroll
    for (int q = P1_GC - 1; q >= 0; --q) L = fmaf(alp[q], L, cs[q]);
    shL[g][ci] = L;
    __syncthreads();

    // 6. carry into group g = suffix over groups j > g
    float X = 0.0f;
#pragma unroll
    for (int j = P1_NG - 1; j >= 1; --j)
        if (j > g) X = fmaf(shG[j], X, shL[j][ci]);

    // 7. chunk-level replay with carry, store rstart[b, g*16+q, c]
    float* rs = rstart + ((size_t)b * NCH + g * P1_GC) * NC + (ctile * 32 + ci);
    float carry = X;
#pragma unroll
    for (int q = P1_GC - 1; q >= 0; --q) {
        carry = fmaf(alp[q], carry, cs[q]);
        rs[(size_t)q * NC] = carry;
    }
}

// ---------------------------------------------------------------------------
// Phase 2: fused scan + soft-CE loss, ACTIVE-SEGMENT ONLY — R11 structure
// (CL=16, 1024 blocks x 4 waves, per-row reductions) + un-confounded head
// fixes: vectorized evraw staging, early global p-loads so the first two
// pred prefetches issue before the staging barrier, wave-uniform pv branch.
// ---------------------------------------------------------------------------
__global__ __launch_bounds__(256) void tdl_loss_kernel(
    const float* __restrict__ pred, const float* __restrict__ target,
    const float* __restrict__ rstart, float* __restrict__ partials)
{
    const int blk = blockIdx.x;
    const int b = blk >> 8;              // / NCH
    const int k = blk & (NCH - 1);
    const int s0 = k * CL;
    const int tid = threadIdx.x;
    const int wv  = (tid >> 6) & 1;      // 0: H-pair, 1: W-pair
    const int rh  = tid >> 7;            // 0: rows 15..8, 1: rows 7..0
    const int ln  = tid & 63;

    __shared__ f32x4 evraw[CL + 1];      // staged {t,h,w,p}
    __shared__ f32x4 ev[CL];             // {dec, p, h, w}
    __shared__ float sh4[4];

    const int lc   = ln * 4;             // lane offset within a 256-ch quarter
    const int segA = wv * 2;             // even segment of my pair
    const size_t pbase = (size_t)b * NS * NC;
    const int itop = rh ? (CL / 2 - 1) : (CL - 1);  // 7 or 15

    // EARLY: p for my first two rows straight from global -> first two pred
    // prefetches issue before the staging barrier.
    const float pt0 = target[((size_t)b * NS + s0 + itop) * 4 + 3];
    const float pt1 = target[((size_t)b * NS + s0 + itop - 1) * 4 + 3];

    f32x4 pf0[2], pf1[2];
    {
        const float* pr = pred + pbase + (size_t)(s0 + itop) * NC
                          + (segA + (int)pt0) * 512 + lc;
        pf0[0] = *(const f32x4*)pr; pf0[1] = *(const f32x4*)(pr + 256);
        const float* pr2 = pred + pbase + (size_t)(s0 + itop - 1) * NC
                           + (segA + (int)pt1) * 512 + lc;
        pf1[0] = *(const f32x4*)pr2; pf1[1] = *(const f32x4*)(pr2 + 256);
    }

    // carry init = r[b,(k+1)*CL, my channels] (zero for last chunk)
    float vA[8], vB[8];
    if (k == NCH - 1) {
#pragma unroll
        for (int j = 0; j < 8; ++j) { vA[j] = 0.0f; vB[j] = 0.0f; }
    } else {
        const float* rrow = rstart + ((size_t)b * NCH + k + 1) * NC;
#pragma unroll
        for (int q = 0; q < 2; ++q) {
            f32x4 ra = *(const f32x4*)(rrow + segA * 512 + q * 256 + lc);
            f32x4 rb = *(const f32x4*)(rrow + (segA + 1) * 512 + q * 256 + lc);
#pragma unroll
            for (int j = 0; j < 4; ++j) {
                vA[q*4+j] = ra[j] * LOG2E;
                vB[q*4+j] = rb[j] * LOG2E;
            }
        }
    }

    // stage CL+1 raw event rows (vectorized f32x4, 17 threads, one round)
    if (tid <= CL) {
        int s = s0 + tid;
        if (s < NS) evraw[tid] = *((const f32x4*)target + (size_t)b * NS + s);
        else        { f32x4 z = {0,0,0,0}; evraw[tid] = z; }
    }
    __syncthreads();
    if (tid < CL) {
        f32x4 r = evraw[tid];
        int s = s0 + tid;
        float dec = (s == NS - 1 || s == 0) ? 0.0f
                   : __expf(-(evraw[tid + 1].x - r.x) * INV_TEMP);
        f32x4 e; e.x = dec; e.y = r.w; e.z = r.y; e.w = r.z;  // {dec,p,h,w}
        ev[tid] = e;
    }
    __syncthreads();

    // rh=1 waves: replay rows 15..8 scan-only to derive carry at row 7
    if (rh) {
#pragma unroll
        for (int i = CL - 1; i >= CL / 2; --i) {
            f32x4 e = ev[i];
            const float d    = e.x;
            const float pv   = e.y;
            const float idxf = wv ? e.w : e.z;
            const float aA = (1.0f - pv) * LOG2E;
            const float aB = pv * LOG2E;
#pragma unroll
            for (int q = 0; q < 2; ++q) {
#pragma unroll
                for (int j = 0; j < 4; ++j) {
                    const int id = q * 4 + j;
                    const float myc = (float)(q * 256 + lc + j);
                    const bool m = (idxf == myc);
                    vA[id] = fmaf(vA[id], d, m ? aA : 0.0f);
                    vB[id] = fmaf(vB[id], d, m ? aB : 0.0f);
                }
            }
        }
    }

    float acc = 0.0f;
#pragma unroll
    for (int r = 0; r < 8; ++r) {
        const int i = itop - r;
        f32x4 cur[2];
        cur[0] = pf0[0]; cur[1] = pf0[1];
        pf0[0] = pf1[0]; pf0[1] = pf1[1];
        if (r < 6) {                     // row i-2 still in my range
            const int pa = (int)ev[i - 2].y;
            const float* pr = pred + pbase + (size_t)(s0 + i - 2) * NC
                              + (segA + pa) * 512 + lc;
            pf1[0] = *(const f32x4*)pr; pf1[1] = *(const f32x4*)(pr + 256);
        }

        f32x4 e = ev[i];
        const float d    = e.x;
        const float pv   = e.y;                    // 0.0 or 1.0 exactly
        const float idxf = wv ? e.w : e.z;         // w for W-pair, h for H-pair
        const float aA = (1.0f - pv) * LOG2E;
        const float aB = pv * LOG2E;

        // scan update for both segments (always)
#pragma unroll
        for (int q = 0; q < 2; ++q) {
#pragma unroll
            for (int j = 0; j < 4; ++j) {
                const int id = q * 4 + j;
                const float myc = (float)(q * 256 + lc + j);
                const bool m = (idxf == myc);
                vA[id] = fmaf(vA[id], d, m ? aA : 0.0f);
                vB[id] = fmaf(vB[id], d, m ? aB : 0.0f);
            }
        }

        // loss body for the ACTIVE segment only (wave-uniform branch)
        float ser = 0.0f, dot = 0.0f, sep = 0.0f;
#define ROW_BODY(V)                                                        \
        _Pragma("unroll")                                                  \
        for (int q = 0; q < 2; ++q) {                                      \
            _Pragma("unroll")                                              \
            for (int j = 0; j < 4; ++j) {                                  \
                const float ex = exp2f(V[q * 4 + j]);                      \
                const float pj = cur[q][j];                                \
                ser += ex;                                                 \
                dot = fmaf(ex, pj, dot);                                   \
                sep += __expf(pj);                                         \
            }                                                              \
        }
        if (pv != 0.0f) { ROW_BODY(vB) } else { ROW_BODY(vA) }
#undef ROW_BODY

        // full-wave 64-lane reductions (active segment = 512 ch = 64 x 8)
#pragma unroll
        for (int off = 32; off > 0; off >>= 1) {
            ser += __shfl_xor(ser, off, 64);
            dot += __shfl_xor(dot, off, 64);
            sep += __shfl_xor(sep, off, 64);
        }
        acc += __logf(sep) - dot * __builtin_amdgcn_rcpf(ser);
    }

    if (ln == 0) sh4[tid >> 6] = acc;    // one writer per wave
    __syncthreads();
    if (tid == 0) partials[blk] = sh4[0] + sh4[1] + sh4[2] + sh4[3];
}

// ---------------------------------------------------------------------------
// Phase 3: tiny reduce — 1 block, 256 threads, 4 KB of partials -> out[0].
// ---------------------------------------------------------------------------
__global__ __launch_bounds__(256) void tdl_reduce_kernel(
    const float* __restrict__ partials, float* __restrict__ out)
{
    const int tid = threadIdx.x;
    __shared__ float sh4[4];

    float s = 0.0f;
#pragma unroll
    for (int i = 0; i < LOSS_NBLK / 256; ++i)
        s += partials[i * 256 + tid];
#pragma unroll
    for (int off = 32; off > 0; off >>= 1)
        s += __shfl_xor(s, off, 64);
    if ((tid & 63) == 0) sh4[tid >> 6] = s;
    __syncthreads();
    if (tid == 0)
        out[0] = (sh4[0] + sh4[1] + sh4[2] + sh4[3])
                 * (1.0f / ((float)NB * (float)NS));
}

// ---------------------------------------------------------------------------
extern "C" void kernel_launch(void* const* d_in, const int* in_sizes, int n_in,
                              void* d_out, int out_size, void* d_ws, size_t ws_size,
                              hipStream_t stream)
{
    const float* pred   = (const float*)d_in[0];
    const float* target = (const float*)d_in[1];
    float* out    = (float*)d_out;
    float* rstart = (float*)d_ws;                       // 8 MiB
    float* partials = rstart + (size_t)NB * NCH * NC;   // 4 KiB

    tdl_scan_kernel<<<NB * 64, 512, 0, stream>>>(target, rstart);
    tdl_loss_kernel<<<NB * NCH, 256, 0, stream>>>(pred, target, rstart, partials);
    tdl_reduce_kernel<<<1, 256, 0, stream>>>(partials, out);
}

// Round 16
// 31.005 us; speedup vs baseline: 1.3164x; 1.0550x over previous
//
#include <hip/hip_runtime.h>
#include <math.h>

#define NC 2048            // 2H + 2W (H = W = 512)
#define NB 4
#define NS 4096
#define INV_TEMP (1.0f / 256.0f)
#define LOG2E 1.44269504088896340736f
#define CL 16              // chunk length (rows per loss block)
#define NCH (NS / CL)      // 256 chunks per batch
#define P1_NG 16           // scan groups per P1 block (512 thr / 32 ch)
#define P1_GS (NS / P1_NG) // 256 s per group
#define P1_GC (P1_GS / CL) // 16 chunks per group
#define LOSS_NBLK (NB * NCH)   // 1024 loss blocks

typedef float f32x4 __attribute__((ext_vector_type(4)));
typedef float f32x2 __attribute__((ext_vector_type(2)));

// 64-lane wave sum on the VALU pipe (DPP), no DS-pipe traffic.
// After the sequence, lane 63 holds the full sum; readlane 63 -> uniform.
// s_nop 1 guards the VALU-write -> DPP-read hazard (2 wait states).
#define WAVE_SUM_DPP(x)                                                       \
    asm volatile("s_nop 1\n\t"                                                \
                 "v_add_f32 %0, %0, %0 row_shr:1 bound_ctrl:0" : "+v"(x));    \
    asm volatile("s_nop 1\n\t"                                                \
                 "v_add_f32 %0, %0, %0 row_shr:2 bound_ctrl:0" : "+v"(x));    \
    asm volatile("s_nop 1\n\t"                                                \
                 "v_add_f32 %0, %0, %0 row_shr:4 bound_ctrl:0" : "+v"(x));    \
    asm volatile("s_nop 1\n\t"                                                \
                 "v_add_f32 %0, %0, %0 row_shr:8 bound_ctrl:0" : "+v"(x));    \
    asm volatile("s_nop 1\n\t"                                                \
                 "v_add_f32 %0, %0, %0 row_bcast:15 row_mask:0xa" : "+v"(x)); \
    asm volatile("s_nop 1\n\t"                                                \
                 "v_add_f32 %0, %0, %0 row_bcast:31 row_mask:0xc" : "+v"(x));

__device__ __forceinline__ float wave_total(float x)
{
    return __uint_as_float(__builtin_amdgcn_readlane(__float_as_uint(x), 63));
}

// ---------------------------------------------------------------------------
// Phase 1: per-(b, 32-channel tile) block.  (verbatim R11 — best config.)
// p in {0,1} exactly -> pack {dec, enc} as f32x2 over the staged buffer;
// per-chunk suffix sums + hierarchical scan -> rstart.
// ---------------------------------------------------------------------------
__global__ __launch_bounds__(512) void tdl_scan_kernel(
    const float* __restrict__ target, float* __restrict__ rstart)
{
    const int b     = blockIdx.x >> 6;   // 64 channel-tiles per batch
    const int ctile = blockIdx.x & 63;
    const int tid = threadIdx.x;
    const int ci  = tid & 31;            // channel within tile
    const int g   = tid >> 5;            // scan group (0..15)

    __shared__ float shbuf[NS * 4];      // 64 KB: f32x4 ev[NS] then f32x2 pk[NS]
    __shared__ float shL[P1_NG][32];
    __shared__ float shG[P1_NG];
    f32x4* ev = (f32x4*)shbuf;
    f32x2* pk = (f32x2*)shbuf;

    const int  seg    = ctile >> 4;                       // 0..3
    const bool useH   = (seg < 2);
    const float segPar = (float)(seg & 1);
    const float crel  = (float)(((ctile & 15) << 5) + ci); // in-segment channel

    const float* tb = target + (size_t)b * NS * 4;

#pragma unroll
    for (int m = 0; m < 8; ++m) {
        int s = m * 512 + tid;
        ev[s] = *((const f32x4*)tb + s);
    }
    __syncthreads();

    float dec_r[8], enc_r[8];
#pragma unroll
    for (int m = 0; m < 8; ++m) {
        int s = m * 512 + tid;
        f32x4 e = ev[s];
        dec_r[m] = (s == NS - 1) ? 0.0f
                  : __expf(-(ev[s + 1].x - e.x) * INV_TEMP);
        enc_r[m] = (e.w == segPar) ? (useH ? e.y : e.z) : -1.0f;
    }
    float alp[P1_GC];
    {
        const int gs = g * P1_GS;
#pragma unroll
        for (int q = 0; q < P1_GC; ++q) {
            int se = gs + q * CL;
            alp[q] = (g == P1_NG - 1 && q == P1_GC - 1) ? 0.0f
                     : __expf(-(ev[se + CL].x - ev[se].x) * INV_TEMP);
        }
        if (ci == 0) {
            shG[g] = (g == P1_NG - 1) ? 0.0f
                     : __expf(-(ev[gs + P1_GS].x - ev[gs].x) * INV_TEMP);
        }
    }
    __syncthreads();

#pragma unroll
    for (int m = 0; m < 8; ++m) {
        int s = m * 512 + tid;
        f32x2 v; v.x = dec_r[m]; v.y = enc_r[m];
        pk[s] = v;
    }
    __syncthreads();

    float cs[P1_GC];
    {
        const int gs = g * P1_GS;
#pragma unroll
        for (int q = P1_GC - 1; q >= 0; --q) {
            float v = 0.0f;
            const int base = gs + q * CL;
#pragma unroll
            for (int i = CL - 1; i >= 0; --i) {
                f32x2 e = pk[base + i];
                v = fmaf(v, e.x, (e.y == crel) ? 1.0f : 0.0f);
            }
            cs[q] = v;
        }
    }

    float L = 0.0f;
#pragma unroll
    for (int q = P1_GC - 1; q >= 0; --q) L = fmaf(alp[q], L, cs[q]);
    shL[g][ci] = L;
    __syncthreads();

    float X = 0.0f;
#pragma unroll
    for (int j = P1_NG - 1; j >= 1; --j)
        if (j > g) X = fmaf(shG[j], X, shL[j][ci]);

    float* rs = rstart + ((size_t)b * NCH + g * P1_GC) * NC + (ctile * 32 + ci);
    float carry = X;
#pragma unroll
    for (int q = P1_GC - 1; q >= 0; --q) {
        carry = fmaf(alp[q], carry, cs[q]);
        rs[(size_t)q * NC] = carry;
    }
}

// ---------------------------------------------------------------------------
// Phase 2: fused scan + soft-CE loss, ACTIVE-SEGMENT ONLY — R11 structure
// (CL=16, 1024 blocks x 4 waves). ONLY change vs R11: the three 6-level
// __shfl_xor trees (18 DS-pipe ops/row; 2304 DS instr per CU at 16 waves/CU,
// on the CU-SHARED LDS pipe) are replaced by DPP VALU-pipe wave sums.
// ---------------------------------------------------------------------------
__global__ __launch_bounds__(256) void tdl_loss_kernel(
    const float* __restrict__ pred, const float* __restrict__ target,
    const float* __restrict__ rstart, float* __restrict__ partials)
{
    const int blk = blockIdx.x;
    const int b = blk >> 8;              // / NCH
    const int k = blk & (NCH - 1);
    const int s0 = k * CL;
    const int tid = threadIdx.x;
    const int wv  = (tid >> 6) & 1;      // 0: H-pair, 1: W-pair
    const int rh  = tid >> 7;            // 0: rows 15..8, 1: rows 7..0
    const int ln  = tid & 63;

    __shared__ f32x4 ev[CL];             // {dec, p, h, w}
    __shared__ float sh4[4];

    if (tid < CL) {
        const float* tg = target + ((size_t)b * NS + s0 + tid) * 4;
        float t0 = tg[0];
        int s = s0 + tid;
        float dec = (s == NS - 1 || s == 0) ? 0.0f
                   : __expf(-(tg[4] - t0) * INV_TEMP);   // tg[4] = t[s+1]
        f32x4 e; e.x = dec; e.y = tg[3]; e.z = tg[1]; e.w = tg[2];
        ev[tid] = e;
    }
    __syncthreads();

    const int lc   = ln * 4;             // lane offset within a 256-ch quarter
    const int segA = wv * 2;             // even segment of my pair
    const size_t pbase = (size_t)b * NS * NC;

    // scan state (exp2 domain) for both segments of the pair
    float vA[8], vB[8];
    if (k == NCH - 1) {
#pragma unroll
        for (int j = 0; j < 8; ++j) { vA[j] = 0.0f; vB[j] = 0.0f; }
    } else {
        const float* rrow = rstart + ((size_t)b * NCH + k + 1) * NC;
#pragma unroll
        for (int q = 0; q < 2; ++q) {
            f32x4 ra = *(const f32x4*)(rrow + segA * 512 + q * 256 + lc);
            f32x4 rb = *(const f32x4*)(rrow + (segA + 1) * 512 + q * 256 + lc);
#pragma unroll
            for (int j = 0; j < 4; ++j) {
                vA[q*4+j] = ra[j] * LOG2E;
                vB[q*4+j] = rb[j] * LOG2E;
            }
        }
    }

    // rh=1 waves: replay rows 15..8 scan-only to derive carry at row 7
    if (rh) {
#pragma unroll
        for (int i = CL - 1; i >= CL / 2; --i) {
            f32x4 e = ev[i];
            const float d    = e.x;
            const float pv   = e.y;
            const float idxf = wv ? e.w : e.z;
            const float aA = (1.0f - pv) * LOG2E;
            const float aB = pv * LOG2E;
#pragma unroll
            for (int q = 0; q < 2; ++q) {
#pragma unroll
                for (int j = 0; j < 4; ++j) {
                    const int id = q * 4 + j;
                    const float myc = (float)(q * 256 + lc + j);
                    const bool m = (idxf == myc);
                    vA[id] = fmaf(vA[id], d, m ? aA : 0.0f);
                    vB[id] = fmaf(vB[id], d, m ? aB : 0.0f);
                }
            }
        }
    }

    const int itop = rh ? (CL / 2 - 1) : (CL - 1);  // 7 or 15

    // depth-2 prefetch of the ACTIVE segment's pred rows
    f32x4 pf0[2], pf1[2];
    {
        const int paT = (int)ev[itop].y;
        const float* pr = pred + pbase + (size_t)(s0 + itop) * NC
                          + (segA + paT) * 512 + lc;
        pf0[0] = *(const f32x4*)pr; pf0[1] = *(const f32x4*)(pr + 256);
        const int paU = (int)ev[itop - 1].y;
        const float* pr2 = pred + pbase + (size_t)(s0 + itop - 1) * NC
                           + (segA + paU) * 512 + lc;
        pf1[0] = *(const f32x4*)pr2; pf1[1] = *(const f32x4*)(pr2 + 256);
    }

    float acc = 0.0f;
#pragma unroll
    for (int r = 0; r < 8; ++r) {
        const int i = itop - r;
        f32x4 cur[2];
        cur[0] = pf0[0]; cur[1] = pf0[1];
        pf0[0] = pf1[0]; pf0[1] = pf1[1];
        if (r < 6) {                     // row i-2 still in my range
            const int pa = (int)ev[i - 2].y;
            const float* pr = pred + pbase + (size_t)(s0 + i - 2) * NC
                              + (segA + pa) * 512 + lc;
            pf1[0] = *(const f32x4*)pr; pf1[1] = *(const f32x4*)(pr + 256);
        }

        f32x4 e = ev[i];
        const float d    = e.x;
        const float pv   = e.y;                    // 0.0 or 1.0 exactly
        const float idxf = wv ? e.w : e.z;         // w for W-pair, h for H-pair
        const float aA = (1.0f - pv) * LOG2E;
        const float aB = pv * LOG2E;

        float ser = 0.0f, dot = 0.0f, sep = 0.0f;
#pragma unroll
        for (int q = 0; q < 2; ++q) {
#pragma unroll
            for (int j = 0; j < 4; ++j) {
                const int id = q * 4 + j;
                const float myc = (float)(q * 256 + lc + j);
                const bool m = (idxf == myc);
                vA[id] = fmaf(vA[id], d, m ? aA : 0.0f);  // scan both segs
                vB[id] = fmaf(vB[id], d, m ? aB : 0.0f);
                const float vs = (pv != 0.0f) ? vB[id] : vA[id];  // active
                const float ex = exp2f(vs);
                const float pj = cur[q][j];
                ser += ex;
                dot = fmaf(ex, pj, dot);
                sep += __expf(pj);
            }
        }

        // 64-lane reductions on the VALU pipe (DPP), no DS traffic
        WAVE_SUM_DPP(ser)
        WAVE_SUM_DPP(dot)
        WAVE_SUM_DPP(sep)
        const float serT = wave_total(ser);
        const float dotT = wave_total(dot);
        const float sepT = wave_total(sep);
        acc += __logf(sepT) - dotT * __builtin_amdgcn_rcpf(serT);
    }

    if (ln == 0) sh4[tid >> 6] = acc;    // one writer per wave
    __syncthreads();
    if (tid == 0) partials[blk] = sh4[0] + sh4[1] + sh4[2] + sh4[3];
}

// ---------------------------------------------------------------------------
// Phase 3: tiny reduce — 1 block, 256 threads, 4 KB of partials -> out[0].
// ---------------------------------------------------------------------------
__global__ __launch_bounds__(256) void tdl_reduce_kernel(
    const float* __restrict__ partials, float* __restrict__ out)
{
    const int tid = threadIdx.x;
    __shared__ float sh4[4];

    float s = 0.0f;
#pragma unroll
    for (int i = 0; i < LOSS_NBLK / 256; ++i)
        s += partials[i * 256 + tid];
#pragma unroll
    for (int off = 32; off > 0; off >>= 1)
        s += __shfl_xor(s, off, 64);
    if ((tid & 63) == 0) sh4[tid >> 6] = s;
    __syncthreads();
    if (tid == 0)
        out[0] = (sh4[0] + sh4[1] + sh4[2] + sh4[3])
                 * (1.0f / ((float)NB * (float)NS));
}

// ---------------------------------------------------------------------------
extern "C" void kernel_launch(void* const* d_in, const int* in_sizes, int n_in,
                              void* d_out, int out_size, void* d_ws, size_t ws_size,
                              hipStream_t stream)
{
    const float* pred   = (const float*)d_in[0];
    const float* target = (const float*)d_in[1];
    float* out    = (float*)d_out;
    float* rstart = (float*)d_ws;                       // 8 MiB
    float* partials = rstart + (size_t)NB * NCH * NC;   // 4 KiB

    tdl_scan_kernel<<<NB * 64, 512, 0, stream>>>(target, rstart);
    tdl_loss_kernel<<<NB * NCH, 256, 0, stream>>>(pred, target, rstart, partials);
    tdl_reduce_kernel<<<1, 256, 0, stream>>>(partials, out);
}